// Round 1
// 446.866 us; speedup vs baseline: 1.0091x; 1.0091x over previous
//
#include <hip/hip_runtime.h>
#include <hip/hip_bf16.h>

#define NN 20000
#define NE 640000

typedef __attribute__((ext_vector_type(8))) short short8v;   // 8 bf16
typedef __attribute__((ext_vector_type(4))) float float4v;

__device__ __forceinline__ float silu_f(float x) {
    return x / (1.0f + __expf(-x));
}

__device__ __forceinline__ unsigned int f2bf16(float f) {
    __hip_bfloat16 b = __float2bfloat16(f);
    return (unsigned int)*(unsigned short*)&b;
}

__device__ __forceinline__ float bfpick(unsigned int v, bool odd) {
    return odd ? __uint_as_float(v & 0xffff0000u) : __uint_as_float(v << 16);
}

// ---------------------------------------------------------------------------
// prep_frags: Wm1 -> bf16 B-fragment image (0.125 folded), computed ONCE.
// ---------------------------------------------------------------------------
__global__ __launch_bounds__(256) void prep_frags(
    const float* __restrict__ Wm1, unsigned int* __restrict__ wm1fg)
{
    int idx = blockIdx.x * 256 + threadIdx.x;     // 0..6143
    int j = idx & 7, lane = (idx >> 3) & 63, sec = idx >> 9;
    int kh = sec / 6, nt = sec % 6;
    int k = kh * 32 + ((lane >> 4) * 8) + j;
    int n = nt * 16 + (lane & 15);
    unsigned int b = f2bf16(Wm1[k * 96 + n] * 0.125f);
    unsigned int other = (unsigned int)__shfl_xor((int)b, 1);
    if ((idx & 1) == 0) wm1fg[idx >> 1] = b | (other << 16);
}

// ---------------------------------------------------------------------------
// Kernel A1: per-node y precompute -> PACKED BF16, plane-major (144 uints).
// ---------------------------------------------------------------------------
__global__ __launch_bounds__(256) void node_y(
    const float* __restrict__ x,
    const float* __restrict__ W10,
    const float* __restrict__ W11,
    const float* __restrict__ W12,
    unsigned int* __restrict__ yAll16)
{
    __shared__ float xs[8][288];
    __shared__ float w10[1024];
    __shared__ float w11[1024];
    __shared__ float w12[1024];
    const int tid = threadIdx.x;
    const int nodeBase = blockIdx.x * 8;

    if (tid < 256) {
        ((float4*)w10)[tid] = ((const float4*)W10)[tid];
        ((float4*)w11)[tid] = ((const float4*)W11)[tid];
        ((float4*)w12)[tid] = ((const float4*)W12)[tid];
    }
    for (int i = tid; i < 576; i += 256) {
        int nl = i / 72, q = i % 72;
        int n = nodeBase + nl;
        float4 v = {0.f, 0.f, 0.f, 0.f};
        if (n < NN) v = ((const float4*)(x + (long)n * 288))[q];
        ((float4*)xs[nl])[q] = v;
    }
    __syncthreads();

    const int nl = tid >> 5, v = tid & 31;
    const int n = nodeBase + nl;
    if (n >= NN) return;

    const float inv_mul = 0.17677669529663687f;  // 1/sqrt(32)
    float vals[9];

    {
        float a = 0.f;
        #pragma unroll
        for (int u = 0; u < 32; ++u) a += xs[nl][u] * w10[u * 32 + v];
        vals[0] = a;
    }
    {
        float a0 = 0.f, a1 = 0.f, a2 = 0.f;
        #pragma unroll
        for (int u = 0; u < 32; ++u) {
            float wv = w11[u * 32 + v];
            a0 += xs[nl][32 + u * 3 + 0] * wv;
            a1 += xs[nl][32 + u * 3 + 1] * wv;
            a2 += xs[nl][32 + u * 3 + 2] * wv;
        }
        vals[1] = a0; vals[2] = a1; vals[3] = a2;
    }
    {
        float a[5] = {0.f, 0.f, 0.f, 0.f, 0.f};
        #pragma unroll
        for (int u = 0; u < 32; ++u) {
            float wv = w12[u * 32 + v];
            #pragma unroll
            for (int m = 0; m < 5; ++m) a[m] += xs[nl][128 + u * 5 + m] * wv;
        }
        #pragma unroll
        for (int m = 0; m < 5; ++m) vals[4 + m] = a[m];
    }

    unsigned int* yrow = yAll16 + (long)n * 144;
    const bool evenLane = ((v & 1) == 0);
    #pragma unroll
    for (int pl = 0; pl < 9; ++pl) {
        float mine  = vals[pl] * inv_mul;
        float other = __shfl_xor(mine, 1);
        if (evenLane)
            yrow[pl * 16 + (v >> 1)] = f2bf16(mine) | (f2bf16(other) << 16);
    }
}

// ---------------------------------------------------------------------------
// Kernel A2: sc GEMM. 64 nodes/block; thread = 8 nodes x 3 cols.
// ---------------------------------------------------------------------------
__global__ __launch_bounds__(256) void node_sc(
    const float* __restrict__ x,
    const float* __restrict__ na,
    const float* __restrict__ scW,
    float* __restrict__ sc)
{
    __shared__ float B[128 * 96];
    __shared__ float x0s[64 * 32];
    __shared__ float nas[64 * 4];
    const int tid = threadIdx.x;
    const int nodeBase = blockIdx.x * 64;

    for (int i = tid; i < 3072; i += 256) {
        int qw = i & 7, rest = i >> 3;
        int t = rest & 3, u = (rest >> 2) & 31, h = rest >> 7;
        float4 v = ((const float4*)scW)[i];
        ((float4*)&B[(u * 4 + t) * 96 + h * 32])[qw] = v;
    }
    for (int i = tid; i < 512; i += 256) {
        int nl = i >> 3, q = i & 7;
        int n = nodeBase + nl;
        float4 v = {0.f, 0.f, 0.f, 0.f};
        if (n < NN) v = ((const float4*)(x + (long)n * 288))[q];
        ((float4*)&x0s[nl * 32])[q] = v;
    }
    for (int i = tid; i < 256; i += 256) {
        int nl = i >> 2, t = i & 3;
        int n = nodeBase + nl;
        nas[i] = (n < NN) ? na[n * 4 + t] : 0.f;
    }
    __syncthreads();

    const int g = tid >> 5, c = tid & 31;
    float nav[8][4];
    #pragma unroll
    for (int j = 0; j < 8; ++j)
        #pragma unroll
        for (int t = 0; t < 4; ++t) nav[j][t] = nas[(g * 8 + j) * 4 + t];

    float acc[3][8];
    #pragma unroll
    for (int cc = 0; cc < 3; ++cc)
        #pragma unroll
        for (int j = 0; j < 8; ++j) acc[cc][j] = 0.f;

    for (int u = 0; u < 32; ++u) {
        float aj[8];
        #pragma unroll
        for (int j = 0; j < 8; ++j) aj[j] = x0s[(g * 8 + j) * 32 + u];
        #pragma unroll
        for (int t = 0; t < 4; ++t) {
            float b0 = B[(u * 4 + t) * 96 + c];
            float b1 = B[(u * 4 + t) * 96 + 32 + c];
            float b2 = B[(u * 4 + t) * 96 + 64 + c];
            #pragma unroll
            for (int j = 0; j < 8; ++j) {
                float p = aj[j] * nav[j][t];
                acc[0][j] += p * b0;
                acc[1][j] += p * b1;
                acc[2][j] += p * b2;
            }
        }
    }

    const float inv_sc = 0.08838834764831845f;  // 1/sqrt(128)
    #pragma unroll
    for (int j = 0; j < 8; ++j) {
        int n = nodeBase + g * 8 + j;
        if (n < NN) {
            #pragma unroll
            for (int cc = 0; cc < 3; ++cc)
                sc[((long)cc * NN + n) * 32 + c] = acc[cc][j] * inv_sc;
        }
    }
}

// ---------------------------------------------------------------------------
// CSR build (dest): histogram -> scan -> scatter ids (+ sorted source).
// ---------------------------------------------------------------------------
__global__ __launch_bounds__(256) void hist_kernel(
    const int* __restrict__ ei, int* __restrict__ counts)
{
    int e = blockIdx.x * 256 + threadIdx.x;
    if (e < NE) atomicAdd(&counts[ei[NE + e]], 1);
}

__global__ __launch_bounds__(1024) void scan_kernel(
    const int* __restrict__ counts, int* __restrict__ offsets)
{
    __shared__ int partial[1024];
    const int t = threadIdx.x;
    const int base = t * 20;          // 1024*20 = 20480 >= NN
    int loc[20];
    int s = 0;
    #pragma unroll
    for (int i = 0; i < 20; ++i) {
        int v = (base + i < NN) ? counts[base + i] : 0;
        loc[i] = s;
        s += v;
    }
    partial[t] = s;
    __syncthreads();
    for (int off = 1; off < 1024; off <<= 1) {
        int v = (t >= off) ? partial[t - off] : 0;
        __syncthreads();
        partial[t] += v;
        __syncthreads();
    }
    int pre = (t == 0) ? 0 : partial[t - 1];
    #pragma unroll
    for (int i = 0; i < 20; ++i)
        if (base + i <= NN) offsets[base + i] = pre + loc[i];
}

__global__ __launch_bounds__(256) void scatter_ids(
    const int* __restrict__ ei, const int* __restrict__ offsets,
    int* __restrict__ cursor, int* __restrict__ sidx, int* __restrict__ ssrc)
{
    int e = blockIdx.x * 256 + threadIdx.x;
    if (e < NE) {
        int d = ei[NE + e];
        int s = ei[e];
        int pos = offsets[d] + atomicAdd(&cursor[d], 1);
        sidx[pos] = e;
        ssrc[pos] = s;
    }
}

// ---------------------------------------------------------------------------
// edge_fused: edge_w + gather_reduce fused. Block owns 8 consecutive nodes =
// one CONTIGUOUS sorted-position range [offs[0], offs[8]). Per 64-edge tile:
//   stage (ee gather, ea gather, ssrc/nl) -> A1 h-frags -> A2 MFMA w-tile in
//   LDS -> B edge-parallel consume (thread = channel u x slice-of-8-edges,
//   run-accumulate + flush-on-node-change into LDS midAcc via ds_add).
// w (former 123 MB wbuf) never touches HBM. Wm1 B-frags read from global
// (12 KB, L1-resident after tile 0). LDS ~30 KB -> 5 blocks/CU.
// ---------------------------------------------------------------------------
__global__ __launch_bounds__(256) void edge_fused(
    const float* __restrict__ ee,
    const float* __restrict__ ea,
    const int*   __restrict__ sidx,
    const int*   __restrict__ ssrc,
    const int*   __restrict__ offsets,
    const float* __restrict__ Wm0,
    const unsigned int* __restrict__ wm1fg,
    const unsigned int* __restrict__ yAll16,
    float* __restrict__ mid)
{
    __shared__ float ees[512];            // [le*8+k]          2 KB
    __shared__ float wm0s[512];           // [k*64+i]          2 KB
    __shared__ unsigned short hsf[4096];  // A-frags           8 KB
    __shared__ unsigned int wtile[3072];  // 64 x 96 bf16     12 KB
    __shared__ float easp[576];           // [le*9+m]        2.25 KB
    __shared__ float midAcc[768];         // 8 nodes x 96      3 KB
    __shared__ int ssh[64];
    __shared__ int nlsh[64];
    __shared__ int offs[9];

    const int tid = threadIdx.x;
    const int nodeBase = blockIdx.x * 8;

    for (int i = tid; i < 512; i += 256) wm0s[i] = Wm0[i];
    for (int i = tid; i < 768; i += 256) midAcc[i] = 0.f;
    if (tid < 9) offs[tid] = offsets[nodeBase + tid];
    __syncthreads();

    const int blkLo = offs[0], blkHi = offs[8];

    const int u = tid & 31, sl = tid >> 5;
    const int p = u >> 1;
    const bool odd = (u & 1);

    for (int t0 = blkLo; t0 < blkHi; t0 += 64) {
        // ---- staging: ssrc/node-id, ee gather, ea gather ----
        for (int i = tid; i < 64; i += 256) {
            int pos = t0 + i;
            int s = (pos < blkHi) ? ssrc[pos] : 0;
            ssh[i] = s;
            int nl = 0;
            #pragma unroll
            for (int q = 1; q < 8; ++q) nl += (pos >= offs[q]);
            nlsh[i] = nl;
        }
        for (int i = tid; i < 512; i += 256) {
            int le = i >> 3, k = i & 7;
            int pos = t0 + le;
            int e = (pos < blkHi) ? sidx[pos] : 0;
            ees[i] = ee[(long)e * 8 + k];
        }
        for (int i = tid; i < 576; i += 256) {
            int le = i / 9, m = i - le * 9;
            int pos = t0 + le;
            int e = (pos < blkHi) ? sidx[pos] : 0;
            easp[i] = ea[(long)e * 9 + m];
        }
        __syncthreads();

        // ---- phase A1: h -> A-frag slots (bf16). thread = (edge, quarter)
        {
            const float inv_sqrt8 = 0.35355339059327373f;
            const int le = tid >> 2, i0 = (tid & 3) * 16;
            const int tile = le >> 4, m = le & 15;
            float emb[8];
            #pragma unroll
            for (int k = 0; k < 8; ++k) emb[k] = ees[le * 8 + k];
            #pragma unroll
            for (int i = 0; i < 16; ++i) {
                int k = i0 + i;
                float t = 0.f;
                #pragma unroll
                for (int q = 0; q < 8; ++q) t += emb[q] * wm0s[q * 64 + k];
                int kh = k >> 5, kq = (k >> 3) & 3, j = k & 7;
                int lane = kq * 16 + m;
                hsf[((tile * 2 + kh) * 64 + lane) * 8 + j] =
                    (unsigned short)f2bf16(silu_f(t * inv_sqrt8));
            }
        }
        __syncthreads();

        // ---- phase A2: MFMA -> wtile (LDS). wave wv = 16-edge subtile.
        {
            unsigned short* wts = (unsigned short*)wtile;
            const unsigned short* wm1f = (const unsigned short*)wm1fg;
            const int wv = tid >> 6, lane = tid & 63;
            const short8v a0 = *(const short8v*)&hsf[((wv * 2 + 0) * 64 + lane) * 8];
            const short8v a1 = *(const short8v*)&hsf[((wv * 2 + 1) * 64 + lane) * 8];
            const int col = lane & 15, rowq = (lane >> 4) * 4;
            #pragma unroll
            for (int nt = 0; nt < 6; ++nt) {
                short8v b0 = *(const short8v*)&wm1f[((0 * 6 + nt) * 64 + lane) * 8];
                short8v b1 = *(const short8v*)&wm1f[((1 * 6 + nt) * 64 + lane) * 8];
                float4v acc = {0.f, 0.f, 0.f, 0.f};
                acc = __builtin_amdgcn_mfma_f32_16x16x32_bf16(a0, b0, acc, 0, 0, 0);
                acc = __builtin_amdgcn_mfma_f32_16x16x32_bf16(a1, b1, acc, 0, 0, 0);
                const int c = nt * 16 + col;
                #pragma unroll
                for (int r = 0; r < 4; ++r)
                    wts[(wv * 16 + rowq + r) * 96 + c] = (unsigned short)f2bf16(acc[r]);
            }
        }
        __syncthreads();

        // ---- phase B: edge-parallel consume. thread = (channel u, slice sl)
        {
            int rem = blkHi - t0 - sl * 8;
            int kmax = rem < 8 ? (rem < 0 ? 0 : rem) : 8;
            int curN = -1;
            float a0 = 0.f, a1 = 0.f, a2 = 0.f;
            for (int k = 0; k < kmax; ++k) {
                int le = sl * 8 + k;
                int nl = nlsh[le];
                if (nl != curN) {
                    if (curN >= 0) {
                        atomicAdd(&midAcc[curN * 96 + u],      a0);
                        atomicAdd(&midAcc[curN * 96 + 32 + u], a1);
                        atomicAdd(&midAcc[curN * 96 + 64 + u], a2);
                    }
                    curN = nl; a0 = 0.f; a1 = 0.f; a2 = 0.f;
                }
                int s = ssh[le];
                const unsigned int* wr = wtile + le * 48;
                const unsigned int* yb = yAll16 + (long)s * 144;
                const float* eav = easp + le * 9;

                float w0 = bfpick(wr[p], odd);
                float w1 = bfpick(wr[16 + p], odd);
                float w2 = bfpick(wr[32 + p], odd);

                a0 += w0 * bfpick(yb[p], odd) * eav[0];

                float d1 = bfpick(yb[16 + p], odd) * eav[1]
                         + bfpick(yb[32 + p], odd) * eav[2]
                         + bfpick(yb[48 + p], odd) * eav[3];
                a1 += w1 * d1;

                float d2 = bfpick(yb[64 + p], odd) * eav[4]
                         + bfpick(yb[80 + p], odd) * eav[5]
                         + bfpick(yb[96 + p], odd) * eav[6]
                         + bfpick(yb[112 + p], odd) * eav[7]
                         + bfpick(yb[128 + p], odd) * eav[8];
                a2 += w2 * d2;
            }
            if (curN >= 0) {
                atomicAdd(&midAcc[curN * 96 + u],      a0);
                atomicAdd(&midAcc[curN * 96 + 32 + u], a1);
                atomicAdd(&midAcc[curN * 96 + 64 + u], a2);
            }
        }
        __syncthreads();   // protect LDS before next tile's staging
    }

    const float invAVG = 0.17677669529663687f;                        // 1/sqrt(32)
    const float cc1    = 0.5773502691896258f * 0.17677669529663687f;  // /sqrt3/sqrt32
    const float cc2    = 0.4472135954999579f * 0.17677669529663687f;  // /sqrt5/sqrt32
    for (int i = tid; i < 768; i += 256) {
        int nl = i / 96, c = i - nl * 96;
        int sec = c >> 5;
        float scale = (sec == 0) ? invAVG : (sec == 1 ? cc1 : cc2);
        mid[(long)(nodeBase + nl) * 96 + c] = midAcc[i] * scale;
    }
}

// ---------------------------------------------------------------------------
// Kernel C: output GEMV + sc + silu. float4 staging.
// ---------------------------------------------------------------------------
__global__ __launch_bounds__(256) void node_out(
    const float* __restrict__ mid,
    const float* __restrict__ sc,
    const float* __restrict__ L0,
    const float* __restrict__ L1,
    const float* __restrict__ L2,
    float* __restrict__ out)
{
    __shared__ float l0[32 * 32];
    __shared__ float l1[64 * 32];
    __shared__ float l2[96 * 32];
    __shared__ float ms[8][96];
    const int tid = threadIdx.x;
    const int nodeBase = blockIdx.x * 8;

    if (tid < 256) ((float4*)l0)[tid] = ((const float4*)L0)[tid];
    for (int i = tid; i < 512; i += 256) ((float4*)l1)[i] = ((const float4*)L1)[i];
    for (int i = tid; i < 768; i += 256) ((float4*)l2)[i] = ((const float4*)L2)[i];
    for (int i = tid; i < 192; i += 256) {
        int nl = i / 24, q = i % 24;
        int n = nodeBase + nl;
        float4 v = {0.f, 0.f, 0.f, 0.f};
        if (n < NN) v = ((const float4*)(mid + (long)n * 96))[q];
        ((float4*)ms[nl])[q] = v;
    }
    __syncthreads();

    const int nl = tid >> 5, wv = tid & 31;
    const int n = nodeBase + nl;
    if (n >= NN) return;

    float a0 = 0.f, a1 = 0.f, a2 = 0.f;
    #pragma unroll
    for (int u = 0; u < 32; ++u) {
        float m = ms[nl][u];
        a0 += m * l0[u * 32 + wv];
        a1 += m * l1[u * 32 + wv];
        a2 += m * l2[u * 32 + wv];
    }
    #pragma unroll
    for (int u = 32; u < 64; ++u) {
        float m = ms[nl][u];
        a1 += m * l1[u * 32 + wv];
        a2 += m * l2[u * 32 + wv];
    }
    #pragma unroll
    for (int u = 64; u < 96; ++u) a2 += ms[nl][u] * l2[u * 32 + wv];

    const float is32 = 0.17677669529663687f;
    const float is64 = 0.125f;
    const float is96 = 0.10206207261596575f;
    const long base = (long)n * 32 + wv;
    out[base]                     = silu_f(a0 * is32 + sc[base]);
    out[(long)NN * 32 + base]     = silu_f(a1 * is64 + sc[(long)NN * 32 + base]);
    out[(long)2 * NN * 32 + base] = silu_f(a2 * is96 + sc[(long)2 * NN * 32 + base]);
}

extern "C" void kernel_launch(void* const* d_in, const int* in_sizes, int n_in,
                              void* d_out, int out_size, void* d_ws, size_t ws_size,
                              hipStream_t stream)
{
    const float* x   = (const float*)d_in[0];
    const float* na  = (const float*)d_in[1];
    const float* ee  = (const float*)d_in[2];
    const float* ea  = (const float*)d_in[3];
    const int*   ei  = (const int*)d_in[4];
    const float* W10 = (const float*)d_in[5];
    const float* W11 = (const float*)d_in[6];
    const float* W12 = (const float*)d_in[7];
    const float* Wm0 = (const float*)d_in[8];
    const float* Wm1 = (const float*)d_in[9];
    const float* L0  = (const float*)d_in[10];
    const float* L1  = (const float*)d_in[11];
    const float* L2  = (const float*)d_in[12];
    const float* scW = (const float*)d_in[13];
    float* out = (float*)d_out;

    unsigned int* yAll16 = (unsigned int*)d_ws;           // NN*144 uints
    float* sc      = (float*)(yAll16 + (size_t)NN * 144); // 3*NN*32 f32
    float* mid     = sc + (size_t)3 * NN * 32;            // NN*96 f32
    int*   counts  = (int*)(mid + (size_t)NN * 96);       // NN  \ one memset
    int*   cursor  = counts + NN;                         // NN  /
    int*   offsets = cursor + NN;                         // NN+1
    int*   sidx    = offsets + NN + 1;                    // NE
    int*   ssrc    = sidx + NE;                           // NE
    unsigned int* wm1fg = (unsigned int*)(ssrc + NE);     // 3072

    hipMemsetAsync(counts, 0, 2 * NN * sizeof(int), stream);

    hist_kernel<<<(NE + 255) / 256, 256, 0, stream>>>(ei, counts);
    scan_kernel<<<1, 1024, 0, stream>>>(counts, offsets);
    scatter_ids<<<(NE + 255) / 256, 256, 0, stream>>>(ei, offsets, cursor, sidx, ssrc);

    prep_frags<<<24, 256, 0, stream>>>(Wm1, wm1fg);
    node_y<<<(NN + 7) / 8, 256, 0, stream>>>(x, W10, W11, W12, yAll16);
    node_sc<<<(NN + 63) / 64, 256, 0, stream>>>(x, na, scW, sc);

    edge_fused<<<NN / 8, 256, 0, stream>>>(ee, ea, sidx, ssrc, offsets,
                                           Wm0, wm1fg, yAll16, mid);

    node_out<<<(NN + 7) / 8, 256, 0, stream>>>(mid, sc, L0, L1, L2, out);
}

// Round 2
// 445.762 us; speedup vs baseline: 1.0116x; 1.0025x over previous
//
#include <hip/hip_runtime.h>
#include <hip/hip_bf16.h>

#define NN 20000
#define NE 640000

typedef __attribute__((ext_vector_type(8))) short short8v;   // 8 bf16
typedef __attribute__((ext_vector_type(4))) float float4v;
typedef __attribute__((ext_vector_type(4))) unsigned int uint4v;

__device__ __forceinline__ float silu_f(float x) {
    return x / (1.0f + __expf(-x));
}

__device__ __forceinline__ unsigned int f2bf16(float f) {
    __hip_bfloat16 b = __float2bfloat16(f);
    return (unsigned int)*(unsigned short*)&b;
}

__device__ __forceinline__ float bfpick(unsigned int v, bool odd) {
    return odd ? __uint_as_float(v & 0xffff0000u) : __uint_as_float(v << 16);
}

// ---------------------------------------------------------------------------
// Kernel A1 (+ edge histogram folded in): per-node y -> packed bf16.
// Grid 2500 x 256 = 640000 threads == NE exactly, so the histogram rides along.
// ---------------------------------------------------------------------------
__global__ __launch_bounds__(256) void node_y(
    const float* __restrict__ x,
    const float* __restrict__ W10,
    const float* __restrict__ W11,
    const float* __restrict__ W12,
    unsigned int* __restrict__ yAll16,
    const int* __restrict__ ei,
    int* __restrict__ counts)
{
    __shared__ float xs[8][288];
    __shared__ float w10[1024];
    __shared__ float w11[1024];
    __shared__ float w12[1024];
    const int tid = threadIdx.x;
    const int nodeBase = blockIdx.x * 8;

    // folded histogram: one edge per thread
    {
        int e = blockIdx.x * 256 + tid;
        atomicAdd(&counts[ei[NE + e]], 1);
    }

    if (tid < 256) {
        ((float4*)w10)[tid] = ((const float4*)W10)[tid];
        ((float4*)w11)[tid] = ((const float4*)W11)[tid];
        ((float4*)w12)[tid] = ((const float4*)W12)[tid];
    }
    for (int i = tid; i < 576; i += 256) {
        int nl = i / 72, q = i % 72;
        int n = nodeBase + nl;
        float4 v = {0.f, 0.f, 0.f, 0.f};
        if (n < NN) v = ((const float4*)(x + (long)n * 288))[q];
        ((float4*)xs[nl])[q] = v;
    }
    __syncthreads();

    const int nl = tid >> 5, v = tid & 31;
    const int n = nodeBase + nl;
    if (n >= NN) return;

    const float inv_mul = 0.17677669529663687f;  // 1/sqrt(32)
    float vals[9];

    {
        float a = 0.f;
        #pragma unroll
        for (int u = 0; u < 32; ++u) a += xs[nl][u] * w10[u * 32 + v];
        vals[0] = a;
    }
    {
        float a0 = 0.f, a1 = 0.f, a2 = 0.f;
        #pragma unroll
        for (int u = 0; u < 32; ++u) {
            float wv = w11[u * 32 + v];
            a0 += xs[nl][32 + u * 3 + 0] * wv;
            a1 += xs[nl][32 + u * 3 + 1] * wv;
            a2 += xs[nl][32 + u * 3 + 2] * wv;
        }
        vals[1] = a0; vals[2] = a1; vals[3] = a2;
    }
    {
        float a[5] = {0.f, 0.f, 0.f, 0.f, 0.f};
        #pragma unroll
        for (int u = 0; u < 32; ++u) {
            float wv = w12[u * 32 + v];
            #pragma unroll
            for (int m = 0; m < 5; ++m) a[m] += xs[nl][128 + u * 5 + m] * wv;
        }
        #pragma unroll
        for (int m = 0; m < 5; ++m) vals[4 + m] = a[m];
    }

    unsigned int* yrow = yAll16 + (long)n * 144;
    const bool evenLane = ((v & 1) == 0);
    #pragma unroll
    for (int pl = 0; pl < 9; ++pl) {
        float mine  = vals[pl] * inv_mul;
        float other = __shfl_xor(mine, 1);
        if (evenLane)
            yrow[pl * 16 + (v >> 1)] = f2bf16(mine) | (f2bf16(other) << 16);
    }
}

// ---------------------------------------------------------------------------
// Kernel A2: sc GEMM. 64 nodes/block; thread = 8 nodes x 3 cols.
// ---------------------------------------------------------------------------
__global__ __launch_bounds__(256) void node_sc(
    const float* __restrict__ x,
    const float* __restrict__ na,
    const float* __restrict__ scW,
    float* __restrict__ sc)
{
    __shared__ float B[128 * 96];
    __shared__ float x0s[64 * 32];
    __shared__ float nas[64 * 4];
    const int tid = threadIdx.x;
    const int nodeBase = blockIdx.x * 64;

    for (int i = tid; i < 3072; i += 256) {
        int qw = i & 7, rest = i >> 3;
        int t = rest & 3, u = (rest >> 2) & 31, h = rest >> 7;
        float4 v = ((const float4*)scW)[i];
        ((float4*)&B[(u * 4 + t) * 96 + h * 32])[qw] = v;
    }
    for (int i = tid; i < 512; i += 256) {
        int nl = i >> 3, q = i & 7;
        int n = nodeBase + nl;
        float4 v = {0.f, 0.f, 0.f, 0.f};
        if (n < NN) v = ((const float4*)(x + (long)n * 288))[q];
        ((float4*)&x0s[nl * 32])[q] = v;
    }
    for (int i = tid; i < 256; i += 256) {
        int nl = i >> 2, t = i & 3;
        int n = nodeBase + nl;
        nas[i] = (n < NN) ? na[n * 4 + t] : 0.f;
    }
    __syncthreads();

    const int g = tid >> 5, c = tid & 31;
    float nav[8][4];
    #pragma unroll
    for (int j = 0; j < 8; ++j)
        #pragma unroll
        for (int t = 0; t < 4; ++t) nav[j][t] = nas[(g * 8 + j) * 4 + t];

    float acc[3][8];
    #pragma unroll
    for (int cc = 0; cc < 3; ++cc)
        #pragma unroll
        for (int j = 0; j < 8; ++j) acc[cc][j] = 0.f;

    for (int u = 0; u < 32; ++u) {
        float aj[8];
        #pragma unroll
        for (int j = 0; j < 8; ++j) aj[j] = x0s[(g * 8 + j) * 32 + u];
        #pragma unroll
        for (int t = 0; t < 4; ++t) {
            float b0 = B[(u * 4 + t) * 96 + c];
            float b1 = B[(u * 4 + t) * 96 + 32 + c];
            float b2 = B[(u * 4 + t) * 96 + 64 + c];
            #pragma unroll
            for (int j = 0; j < 8; ++j) {
                float p = aj[j] * nav[j][t];
                acc[0][j] += p * b0;
                acc[1][j] += p * b1;
                acc[2][j] += p * b2;
            }
        }
    }

    const float inv_sc = 0.08838834764831845f;  // 1/sqrt(128)
    #pragma unroll
    for (int j = 0; j < 8; ++j) {
        int n = nodeBase + g * 8 + j;
        if (n < NN) {
            #pragma unroll
            for (int cc = 0; cc < 3; ++cc)
                sc[((long)cc * NN + n) * 32 + c] = acc[cc][j] * inv_sc;
        }
    }
}

// ---------------------------------------------------------------------------
// scan (block 0) + prep_frags (blocks 1..6) in one launch.
// ---------------------------------------------------------------------------
__global__ __launch_bounds__(1024) void scan_prep(
    const int* __restrict__ counts, int* __restrict__ offsets,
    const float* __restrict__ Wm1, unsigned int* __restrict__ wm1fg)
{
    if (blockIdx.x > 0) {
        int idx = (blockIdx.x - 1) * 1024 + threadIdx.x;   // 0..6143
        int j = idx & 7, lane = (idx >> 3) & 63, sec = idx >> 9;
        int kh = sec / 6, nt = sec % 6;
        int k = kh * 32 + ((lane >> 4) * 8) + j;
        int n = nt * 16 + (lane & 15);
        unsigned int b = f2bf16(Wm1[k * 96 + n] * 0.125f);
        unsigned int other = (unsigned int)__shfl_xor((int)b, 1);
        if ((idx & 1) == 0) wm1fg[idx >> 1] = b | (other << 16);
        return;
    }

    __shared__ int partial[1024];
    const int t = threadIdx.x;
    const int base = t * 20;          // 1024*20 = 20480 >= NN
    int loc[20];
    int s = 0;
    #pragma unroll
    for (int i = 0; i < 20; ++i) {
        int v = (base + i < NN) ? counts[base + i] : 0;
        loc[i] = s;
        s += v;
    }
    partial[t] = s;
    __syncthreads();
    for (int off = 1; off < 1024; off <<= 1) {
        int v = (t >= off) ? partial[t - off] : 0;
        __syncthreads();
        partial[t] += v;
        __syncthreads();
    }
    int pre = (t == 0) ? 0 : partial[t - 1];
    #pragma unroll
    for (int i = 0; i < 20; ++i)
        if (base + i <= NN) offsets[base + i] = pre + loc[i];
}

__global__ __launch_bounds__(256) void scatter_ids(
    const int* __restrict__ ei, const int* __restrict__ offsets,
    int* __restrict__ cursor, int* __restrict__ sidx, int* __restrict__ ssrc)
{
    int e = blockIdx.x * 256 + threadIdx.x;
    if (e < NE) {
        int d = ei[NE + e];
        int s = ei[e];
        int pos = offsets[d] + atomicAdd(&cursor[d], 1);
        sidx[pos] = e;
        ssrc[pos] = s;
    }
}

// ---------------------------------------------------------------------------
// edge_fused v2: BARRIER-FREE main loop. Every phase was already wave-local,
// so each wave independently pipelines its own 16-edge subtiles through
// wave-private LDS regions (same-wave LDS ordering via hw lgkmcnt). 16-20
// independent wave pipelines per CU hide the gather latency by TLP.
//  - h-frags written as 2x ds_write_b128/lane (bank-optimal, was 8-way b16)
//  - wtile stride padded 48->50 uints: conflict-free writes+reads
//  - Wm1 B-frags read from global (L1-resident), ea staged in aligned slot
//  - asm memory fence per iter stops LICM blowing VGPRs on invariant reads
// ---------------------------------------------------------------------------
__global__ __launch_bounds__(256) void edge_fused(
    const float* __restrict__ ee,
    const float* __restrict__ ea,
    const int*   __restrict__ sidx,
    const int*   __restrict__ ssrc,
    const int*   __restrict__ offsets,
    const float* __restrict__ Wm0,
    const unsigned int* __restrict__ wm1fg,
    const unsigned int* __restrict__ yAll16,
    float* __restrict__ mid)
{
    __shared__ float wm0s[512];              // [k8*64 + i]           2 KB
    __shared__ unsigned int hsf[4][512];     // wave-private A-frags  8 KB
    __shared__ unsigned int wtile[4][800];   // 16 rows x 50 uints  12.8 KB
    __shared__ float easp[4][192];           // 16 edges x 12 (pad)   3 KB
    __shared__ float midAcc[768];            // 8 nodes x 96          3 KB
    __shared__ int offsS[9];

    const int tid = threadIdx.x;
    const int wv = tid >> 6, l = tid & 63;
    const int nodeBase = blockIdx.x * 8;

    for (int i = tid; i < 512; i += 256) wm0s[i] = Wm0[i];
    for (int i = tid; i < 768; i += 256) midAcc[i] = 0.f;
    if (tid < 9) offsS[tid] = offsets[nodeBase + tid];
    __syncthreads();

    const int blkLo = offsS[0], blkHi = offsS[8];
    const int of1 = offsS[1], of2 = offsS[2], of3 = offsS[3], of4 = offsS[4];
    const int of5 = offsS[5], of6 = offsS[6], of7 = offsS[7];

    // roles
    const int m16 = l & 15;
    const int u = l & 31, sl = l >> 5;          // phase B
    const int p = u >> 1; const bool odd = (u & 1);
    const int eA = l >> 2, qA = l & 3;          // phase A1
    const int khA = qA >> 1;
    const int kq0 = (qA * 2) & 3, kq1 = (qA * 2 + 1) & 3;
    const int col = l & 15, rowq = (l >> 4) * 4;  // MFMA C layout

    unsigned int* hw  = hsf[wv];
    unsigned int* wt  = wtile[wv];
    float*        eas = easp[wv];
    const unsigned short* wm1f = (const unsigned short*)wm1fg;

    const int nsub = (blkHi - blkLo + 15) >> 4;
    int st = wv;
    int eid16 = 0, s16 = 0;
    if (st < nsub) {
        int pc = blkLo + st * 16 + m16;
        if (pc > blkHi - 1) pc = blkHi - 1;
        eid16 = sidx[pc];
        s16   = ssrc[pc];
    }

    for (; st < nsub; st += 4) {
        asm volatile("" ::: "memory");
        const int p0 = blkLo + st * 16;
        int cnt = blkHi - p0; if (cnt > 16) cnt = 16;
        const int posL = p0 + m16;
        int nl16 = (posL >= of1) + (posL >= of2) + (posL >= of3) + (posL >= of4)
                 + (posL >= of5) + (posL >= of6) + (posL >= of7);

        int sarr[8], nlarr[8];
        #pragma unroll
        for (int k = 0; k < 8; ++k) {
            sarr[k]  = __shfl(s16,  sl * 8 + k);
            nlarr[k] = __shfl(nl16, sl * 8 + k);
        }

        // ---- ee load for this lane's A1 edge ----
        const int eidA = __shfl(eid16, eA);
        float4 e0 = ((const float4*)ee)[(long)eidA * 2];
        float4 e1 = ((const float4*)ee)[(long)eidA * 2 + 1];

        // ---- ea staging into wave-private slot (stride 12, 16B-aligned) ----
        {
            int idx0 = l;        int le0 = idx0 / 9, m0 = idx0 - le0 * 9;
            int idx1 = 64 + l;   int le1 = idx1 / 9, m1 = idx1 - le1 * 9;
            int idx2 = 128 + l;  int le2t = idx2 / 9; int m2 = idx2 - le2t * 9;
            int le2 = le2t & 15;
            int ed0 = __shfl(eid16, le0);
            int ed1 = __shfl(eid16, le1);
            int ed2 = __shfl(eid16, le2);
            eas[le0 * 12 + m0] = ea[(long)ed0 * 9 + m0];
            eas[le1 * 12 + m1] = ea[(long)ed1 * 9 + m1];
            if (l < 16) eas[le2 * 12 + m2] = ea[(long)ed2 * 9 + m2];
        }

        // ---- phase A1: h for edge eA, k in [qA*16, qA*16+16) ----
        {
            const float inv_sqrt8 = 0.35355339059327373f;
            float emb[8] = {e0.x, e0.y, e0.z, e0.w, e1.x, e1.y, e1.z, e1.w};
            uint4v pk0, pk1;
            #pragma unroll
            for (int half = 0; half < 2; ++half) {
                #pragma unroll
                for (int jp = 0; jp < 4; ++jp) {
                    int k = qA * 16 + half * 8 + jp * 2;
                    float2 wv2 = *(const float2*)&wm0s[k];
                    float t0 = emb[0] * wv2.x, t1 = emb[0] * wv2.y;
                    #pragma unroll
                    for (int q = 1; q < 8; ++q) {
                        float2 wq = *(const float2*)&wm0s[q * 64 + k];
                        t0 += emb[q] * wq.x;
                        t1 += emb[q] * wq.y;
                    }
                    unsigned int w = f2bf16(silu_f(t0 * inv_sqrt8))
                                   | (f2bf16(silu_f(t1 * inv_sqrt8)) << 16);
                    if (half == 0) pk0[jp] = w; else pk1[jp] = w;
                }
            }
            *(uint4v*)&hw[(khA * 64 + kq0 * 16 + eA) * 4] = pk0;
            *(uint4v*)&hw[(khA * 64 + kq1 * 16 + eA) * 4] = pk1;
        }

        // ---- phase A2: MFMA -> wtile (wave-private, stride 50) ----
        {
            const short8v a0 = *(const short8v*)&hw[(0 * 64 + l) * 4];
            const short8v a1 = *(const short8v*)&hw[(1 * 64 + l) * 4];
            #pragma unroll
            for (int nt = 0; nt < 6; ++nt) {
                short8v b0 = *(const short8v*)&wm1f[((0 * 6 + nt) * 64 + l) * 8];
                short8v b1 = *(const short8v*)&wm1f[((1 * 6 + nt) * 64 + l) * 8];
                float4v acc = {0.f, 0.f, 0.f, 0.f};
                acc = __builtin_amdgcn_mfma_f32_16x16x32_bf16(a0, b0, acc, 0, 0, 0);
                acc = __builtin_amdgcn_mfma_f32_16x16x32_bf16(a1, b1, acc, 0, 0, 0);
                #pragma unroll
                for (int r = 0; r < 4; ++r) {
                    float mine  = acc[r];
                    float other = __shfl_xor(mine, 1);
                    if (!(col & 1))
                        wt[(rowq + r) * 50 + nt * 8 + (col >> 1)] =
                            f2bf16(mine) | (f2bf16(other) << 16);
                }
            }
        }

        // ---- prefetch next subtile's ids ----
        int eid16n = 0, s16n = 0;
        {
            int stn = st + 4;
            if (stn < nsub) {
                int pc = blkLo + stn * 16 + m16;
                if (pc > blkHi - 1) pc = blkHi - 1;
                eid16n = sidx[pc];
                s16n   = ssrc[pc];
            }
        }

        // ---- phase B: consume. lane = (channel u, slice sl of 8 edges) ----
        {
            int kmax = cnt - sl * 8;
            kmax = kmax < 0 ? 0 : (kmax > 8 ? 8 : kmax);
            int curN = -1;
            float a0 = 0.f, a1 = 0.f, a2 = 0.f;
            #pragma unroll
            for (int k = 0; k < 8; ++k) {
                if (k >= kmax) break;
                const int le = sl * 8 + k;
                const int nl = nlarr[k];
                if (nl != curN) {
                    if (curN >= 0) {
                        atomicAdd(&midAcc[curN * 96 + u],      a0);
                        atomicAdd(&midAcc[curN * 96 + 32 + u], a1);
                        atomicAdd(&midAcc[curN * 96 + 64 + u], a2);
                    }
                    curN = nl; a0 = 0.f; a1 = 0.f; a2 = 0.f;
                }
                const unsigned int* wr = wt + le * 50;
                const unsigned int* yb = yAll16 + (long)sarr[k] * 144;
                const float* eav = &eas[le * 12];
                float4 ev0 = *(const float4*)&eav[0];
                float4 ev1 = *(const float4*)&eav[4];
                float  ev8 = eav[8];

                float w0 = bfpick(wr[p], odd);
                float w1 = bfpick(wr[16 + p], odd);
                float w2 = bfpick(wr[32 + p], odd);

                a0 += w0 * bfpick(yb[p], odd) * ev0.x;

                float d1 = bfpick(yb[16 + p], odd) * ev0.y
                         + bfpick(yb[32 + p], odd) * ev0.z
                         + bfpick(yb[48 + p], odd) * ev0.w;
                a1 += w1 * d1;

                float d2 = bfpick(yb[64 + p], odd) * ev1.x
                         + bfpick(yb[80 + p], odd) * ev1.y
                         + bfpick(yb[96 + p], odd) * ev1.z
                         + bfpick(yb[112 + p], odd) * ev1.w
                         + bfpick(yb[128 + p], odd) * ev8;
                a2 += w2 * d2;
            }
            if (curN >= 0) {
                atomicAdd(&midAcc[curN * 96 + u],      a0);
                atomicAdd(&midAcc[curN * 96 + 32 + u], a1);
                atomicAdd(&midAcc[curN * 96 + 64 + u], a2);
            }
        }

        eid16 = eid16n; s16 = s16n;
    }

    __syncthreads();

    const float invAVG = 0.17677669529663687f;                        // 1/sqrt(32)
    const float cc1    = 0.5773502691896258f * 0.17677669529663687f;  // /sqrt3/sqrt32
    const float cc2    = 0.4472135954999579f * 0.17677669529663687f;  // /sqrt5/sqrt32
    for (int i = tid; i < 768; i += 256) {
        int nl = i / 96, c = i - nl * 96;
        int sec = c >> 5;
        float scale = (sec == 0) ? invAVG : (sec == 1 ? cc1 : cc2);
        mid[(long)(nodeBase + nl) * 96 + c] = midAcc[i] * scale;
    }
}

// ---------------------------------------------------------------------------
// Kernel C: output GEMV + sc + silu. float4 staging.
// ---------------------------------------------------------------------------
__global__ __launch_bounds__(256) void node_out(
    const float* __restrict__ mid,
    const float* __restrict__ sc,
    const float* __restrict__ L0,
    const float* __restrict__ L1,
    const float* __restrict__ L2,
    float* __restrict__ out)
{
    __shared__ float l0[32 * 32];
    __shared__ float l1[64 * 32];
    __shared__ float l2[96 * 32];
    __shared__ float ms[8][96];
    const int tid = threadIdx.x;
    const int nodeBase = blockIdx.x * 8;

    if (tid < 256) ((float4*)l0)[tid] = ((const float4*)L0)[tid];
    for (int i = tid; i < 512; i += 256) ((float4*)l1)[i] = ((const float4*)L1)[i];
    for (int i = tid; i < 768; i += 256) ((float4*)l2)[i] = ((const float4*)L2)[i];
    for (int i = tid; i < 192; i += 256) {
        int nl = i / 24, q = i % 24;
        int n = nodeBase + nl;
        float4 v = {0.f, 0.f, 0.f, 0.f};
        if (n < NN) v = ((const float4*)(mid + (long)n * 96))[q];
        ((float4*)ms[nl])[q] = v;
    }
    __syncthreads();

    const int nl = tid >> 5, wv = tid & 31;
    const int n = nodeBase + nl;
    if (n >= NN) return;

    float a0 = 0.f, a1 = 0.f, a2 = 0.f;
    #pragma unroll
    for (int u = 0; u < 32; ++u) {
        float m = ms[nl][u];
        a0 += m * l0[u * 32 + wv];
        a1 += m * l1[u * 32 + wv];
        a2 += m * l2[u * 32 + wv];
    }
    #pragma unroll
    for (int u = 32; u < 64; ++u) {
        float m = ms[nl][u];
        a1 += m * l1[u * 32 + wv];
        a2 += m * l2[u * 32 + wv];
    }
    #pragma unroll
    for (int u = 64; u < 96; ++u) a2 += ms[nl][u] * l2[u * 32 + wv];

    const float is32 = 0.17677669529663687f;
    const float is64 = 0.125f;
    const float is96 = 0.10206207261596575f;
    const long base = (long)n * 32 + wv;
    out[base]                     = silu_f(a0 * is32 + sc[base]);
    out[(long)NN * 32 + base]     = silu_f(a1 * is64 + sc[(long)NN * 32 + base]);
    out[(long)2 * NN * 32 + base] = silu_f(a2 * is96 + sc[(long)2 * NN * 32 + base]);
}

extern "C" void kernel_launch(void* const* d_in, const int* in_sizes, int n_in,
                              void* d_out, int out_size, void* d_ws, size_t ws_size,
                              hipStream_t stream)
{
    const float* x   = (const float*)d_in[0];
    const float* na  = (const float*)d_in[1];
    const float* ee  = (const float*)d_in[2];
    const float* ea  = (const float*)d_in[3];
    const int*   ei  = (const int*)d_in[4];
    const float* W10 = (const float*)d_in[5];
    const float* W11 = (const float*)d_in[6];
    const float* W12 = (const float*)d_in[7];
    const float* Wm0 = (const float*)d_in[8];
    const float* Wm1 = (const float*)d_in[9];
    const float* L0  = (const float*)d_in[10];
    const float* L1  = (const float*)d_in[11];
    const float* L2  = (const float*)d_in[12];
    const float* scW = (const float*)d_in[13];
    float* out = (float*)d_out;

    unsigned int* yAll16 = (unsigned int*)d_ws;           // NN*144 uints
    float* sc      = (float*)(yAll16 + (size_t)NN * 144); // 3*NN*32 f32
    float* mid     = sc + (size_t)3 * NN * 32;            // NN*96 f32
    int*   counts  = (int*)(mid + (size_t)NN * 96);       // NN  \ one memset
    int*   cursor  = counts + NN;                         // NN  /
    int*   offsets = cursor + NN;                         // NN+1
    int*   sidx    = offsets + NN + 1;                    // NE
    int*   ssrc    = sidx + NE;                           // NE
    unsigned int* wm1fg = (unsigned int*)(ssrc + NE);     // 3072

    hipMemsetAsync(counts, 0, 2 * NN * sizeof(int), stream);

    node_y<<<(NN + 7) / 8, 256, 0, stream>>>(x, W10, W11, W12, yAll16, ei, counts);
    scan_prep<<<7, 1024, 0, stream>>>(counts, offsets, Wm1, wm1fg);
    scatter_ids<<<(NE + 255) / 256, 256, 0, stream>>>(ei, offsets, cursor, sidx, ssrc);
    node_sc<<<(NN + 63) / 64, 256, 0, stream>>>(x, na, scW, sc);

    edge_fused<<<NN / 8, 256, 0, stream>>>(ee, ea, sidx, ssrc, offsets,
                                           Wm0, wm1fg, yAll16, mid);

    node_out<<<(NN + 7) / 8, 256, 0, stream>>>(mid, sc, L0, L1, L2, out);
}